// Round 1
// baseline (119.783 us; speedup 1.0000x reference)
//
#include <hip/hip_runtime.h>

// Problem constants from the reference:
//   images: (B=8, H=128, W=128, C=32) float32
//   k=5, pad=2, out: (B, H, W, k*k*C=800) float32
// out[b,h,w,(kh*5+kw)*32+c] = images[b, h+kh-2, w+kw-2, c]  (0 if OOB)

constexpr int KB_ = 5;
constexpr int PAD = 2;
constexpr int CH  = 32;
constexpr int HH  = 128;
constexpr int WW  = 128;

__global__ void extract_patch_kernel(const float* __restrict__ in,
                                     float* __restrict__ out,
                                     int total4) {
    int tid    = blockIdx.x * blockDim.x + threadIdx.x;
    int stride = gridDim.x * blockDim.x;
    for (int i4 = tid; i4 < total4; i4 += stride) {
        // Decompose flat float4 index: c4 (8) fastest, then kw (5), kh (5),
        // w (128), h (128), b (8).
        int t  = i4;
        int c4 = t & 7;   t >>= 3;     // 32 ch / 4 = 8 float4 per (kh,kw) block
        int kw = t % KB_; t /= KB_;
        int kh = t % KB_; t /= KB_;
        int w  = t & (WW - 1); t >>= 7;
        int h  = t & (HH - 1); t >>= 7;
        int b  = t;

        int row = h + kh - PAD;
        int col = w + kw - PAD;

        float4 v = make_float4(0.f, 0.f, 0.f, 0.f);
        if ((unsigned)row < (unsigned)HH && (unsigned)col < (unsigned)WW) {
            const float* src = in + ((((size_t)b * HH + row) * WW + col) * CH) + c4 * 4;
            v = *reinterpret_cast<const float4*>(src);
        }
        *reinterpret_cast<float4*>(out + (size_t)i4 * 4) = v;
    }
}

extern "C" void kernel_launch(void* const* d_in, const int* in_sizes, int n_in,
                              void* d_out, int out_size, void* d_ws, size_t ws_size,
                              hipStream_t stream) {
    const float* images = (const float*)d_in[0];
    float* out = (float*)d_out;

    int total4 = out_size / 4;            // 26,214,400 float4 stores
    int threads = 256;
    int blocks = (total4 + threads - 1) / threads;
    if (blocks > 2048) blocks = 2048;     // grid-stride, ~8 blocks/CU

    extract_patch_kernel<<<blocks, threads, 0, stream>>>(images, out, total4);
}

// Round 2
// 103.098 us; speedup vs baseline: 1.1618x; 1.1618x over previous
//
#include <hip/hip_runtime.h>

// images: (B=8, H=128, W=128, C=32) float32; k=5, pad=2
// out: (B, H, W, 800) float32
// out[b,h,w,(kh*5+kw)*32+c] = images[b, h+kh-2, w+kw-2, c]  (0 if OOB)

constexpr int KB_ = 5;
constexpr int PAD = 2;
constexpr int CH  = 32;
constexpr int HH  = 128;
constexpr int WW  = 128;
constexpr int UNROLL = 5;

typedef float f32x4 __attribute__((ext_vector_type(4)));

__global__ void __launch_bounds__(256) extract_patch_kernel(
        const float* __restrict__ in, float* __restrict__ out,
        int total4, int iters) {
    const int stride = gridDim.x * blockDim.x;
    const int tid    = blockIdx.x * blockDim.x + threadIdx.x;

    int it = 0;
    for (; it + UNROLL <= iters; it += UNROLL) {
        f32x4 v[UNROLL];
        int   i4s[UNROLL];
        // Phase 1: issue all loads (independent, unconditional — clamped addr)
        #pragma unroll
        for (int u = 0; u < UNROLL; ++u) {
            int i4 = tid + (it + u) * stride;
            i4s[u] = i4;
            int t  = i4;
            int c4 = t & 7;   t >>= 3;
            int kw = t % KB_; t /= KB_;
            int kh = t % KB_; t /= KB_;
            int w  = t & (WW - 1); t >>= 7;
            int h  = t & (HH - 1); t >>= 7;
            int b  = t;

            int row = h + kh - PAD;
            int col = w + kw - PAD;
            bool ok = ((unsigned)row < (unsigned)HH) & ((unsigned)col < (unsigned)WW);
            int rowc = ok ? row : 0;   // clamp so the load is always legal
            int colc = ok ? col : 0;

            const float* src = in + ((((size_t)b * HH + rowc) * WW + colc) * CH) + c4 * 4;
            f32x4 ld = *reinterpret_cast<const f32x4*>(src);
            f32x4 z  = 0.f;
            v[u] = ok ? ld : z;        // cndmask after load, no divergent branch
        }
        // Phase 2: stores (non-temporal — output never re-read; keep input in L2)
        #pragma unroll
        for (int u = 0; u < UNROLL; ++u) {
            __builtin_nontemporal_store(v[u],
                reinterpret_cast<f32x4*>(out + (size_t)i4s[u] * 4));
        }
    }

    // Remainder (not taken for the benchmark shape, kept for safety)
    for (int i4 = tid + it * stride; i4 < total4; i4 += stride) {
        int t  = i4;
        int c4 = t & 7;   t >>= 3;
        int kw = t % KB_; t /= KB_;
        int kh = t % KB_; t /= KB_;
        int w  = t & (WW - 1); t >>= 7;
        int h  = t & (HH - 1); t >>= 7;
        int b  = t;
        int row = h + kh - PAD;
        int col = w + kw - PAD;
        f32x4 v = 0.f;
        if ((unsigned)row < (unsigned)HH && (unsigned)col < (unsigned)WW) {
            const float* src = in + ((((size_t)b * HH + row) * WW + col) * CH) + c4 * 4;
            v = *reinterpret_cast<const f32x4*>(src);
        }
        __builtin_nontemporal_store(v, reinterpret_cast<f32x4*>(out + (size_t)i4 * 4));
    }
}

extern "C" void kernel_launch(void* const* d_in, const int* in_sizes, int n_in,
                              void* d_out, int out_size, void* d_ws, size_t ws_size,
                              hipStream_t stream) {
    const float* images = (const float*)d_in[0];
    float* out = (float*)d_out;

    int total4  = out_size / 4;          // 26,214,400 float4 stores
    int threads = 256;
    int blocks  = 2048;                  // 524,288 threads → exactly 50 iters/thread
    int stride  = blocks * threads;
    int iters   = total4 / stride;       // = 50 for the benchmark shape

    extract_patch_kernel<<<blocks, threads, 0, stream>>>(images, out, total4, iters);
}

// Round 3
// 81.976 us; speedup vs baseline: 1.4612x; 1.2577x over previous
//
#include <hip/hip_runtime.h>

// images: (B=8, H=128, W=128, C=32) f32; k=5, pad=2; out: (B,H,W,800) f32
// out[b,h,w,(kh*5+kw)*32+c] = images[b, h+kh-2, w+kw-2, c]  (0 if OOB)
//
// Strategy: 1 block per output row (b,h). Stage the 5 input rows it needs
// (80 KB) into LDS once, then stream 25,600 perfectly-coalesced float4
// stores out of LDS. XCD-chunked block swizzle gives each XCD one image b
// (2.1 MB < 4 MiB L2) so staging reads are L2-local.

constexpr int KK   = 5;
constexpr int PAD  = 2;
constexpr int CH4  = 8;                     // 32 ch = 8 float4
constexpr int HH   = 128, WW = 128, BB = 8;
constexpr int ROW_F4     = WW * CH4;        // 1024 float4 per input row
constexpr int OUT_ROW_F4 = WW * KK * KK * CH4;  // 25600 float4 per output row
constexpr int THREADS    = 512;
constexpr int STAGE_F4   = KK * ROW_F4;     // 5120 float4 = 80 KB
constexpr int NWG        = BB * HH;         // 1024 blocks
constexpr int STORES_PER_THREAD = OUT_ROW_F4 / THREADS;  // 50

typedef float f32x4 __attribute__((ext_vector_type(4)));

__global__ void __launch_bounds__(THREADS) extract_patch_kernel(
        const f32x4* __restrict__ in, f32x4* __restrict__ out) {
    __shared__ f32x4 lds[STAGE_F4];         // 80 KB -> 2 blocks/CU

    // XCD-chunked bijective swizzle (nwg=1024, 8 XCDs, 1024%8==0):
    // round-robin dispatch puts bid%8==x on XCD x; give each XCD a
    // contiguous chunk of (b,h) rows -> XCD owns exactly one image b.
    int bid = blockIdx.x;
    int lin = (bid & 7) * (NWG / 8) + (bid >> 3);
    int b = lin >> 7;
    int h = lin & (HH - 1);

    int tid = threadIdx.x;

    // ---- Stage 5 input rows (h-2..h+2) into LDS, zeros for OOB rows ----
    #pragma unroll
    for (int i = 0; i < STAGE_F4 / THREADS; ++i) {     // 10 iterations
        int j  = tid + i * THREADS;
        int r5 = j >> 10;                              // 0..4 (which row)
        int gr = h + r5 - PAD;
        bool ok = (unsigned)gr < (unsigned)HH;
        int grc = ok ? gr : 0;                         // clamp: load always legal
        f32x4 v = in[(size_t)(b * HH + grc) * ROW_F4 + (j & (ROW_F4 - 1))];
        f32x4 z = 0.f;
        lds[j] = ok ? v : z;
    }
    __syncthreads();

    // ---- Stream output row: 50 coalesced float4 stores per thread ----
    f32x4* rowout = out + (size_t)lin * OUT_ROW_F4;
    #pragma unroll 5
    for (int it = 0; it < STORES_PER_THREAD; ++it) {
        int j  = tid + it * THREADS;                   // 0..25599, lanes contiguous
        int w  = j / 200;                              // 200 float4 per w
        int r  = j - w * 200;
        int kq = r >> 3;                               // kh*5+kw (0..24)
        int c4 = r & 7;
        int kh = (kq * 205) >> 10;                     // kq/5 exact for 0..24
        int kw = kq - kh * 5;
        int pc = w + kw - PAD;                         // padded col, -2..129
        bool ok = (unsigned)pc < (unsigned)WW;
        f32x4 v = lds[kh * ROW_F4 + (pc & (WW - 1)) * CH4 + c4];
        f32x4 z = 0.f;
        v = ok ? v : z;                                // cndmask, branchless
        __builtin_nontemporal_store(v, &rowout[j]);    // don't pollute L2
    }
}

extern "C" void kernel_launch(void* const* d_in, const int* in_sizes, int n_in,
                              void* d_out, int out_size, void* d_ws, size_t ws_size,
                              hipStream_t stream) {
    const f32x4* images = (const f32x4*)d_in[0];
    f32x4* out = (f32x4*)d_out;
    extract_patch_kernel<<<NWG, THREADS, 0, stream>>>(images, out);
}

// Round 4
// 79.778 us; speedup vs baseline: 1.5015x; 1.0276x over previous
//
#include <hip/hip_runtime.h>

// images: (B=8, H=128, W=128, C=32) f32; k=5, pad=2; out: (B,H,W,800) f32
// out[b,h,w,(kh*5+kw)*32+c] = images[b, h+kh-2, w+kw-2, c]  (0 if OOB)
//
// Persistent 4-row blocks: 256 blocks (one per CU) x 1024 threads.
// LDS = 8-slot ring of input rows (slot = global_row & 7, 8x16KB = 128KB).
// Per output row: issue 1-row prefetch load early, stream 25 coalesced
// float4 NT stores/thread from LDS, ds_write prefetch, barrier.
// XCD-chunked swizzle: each XCD owns one image b (2.1 MB < 4 MiB L2).

constexpr int KK   = 5;
constexpr int PAD  = 2;
constexpr int CH4  = 8;                         // 32 ch = 8 float4
constexpr int HH   = 128, WW = 128, BB = 8;
constexpr int ROW_F4     = WW * CH4;            // 1024 float4 = 16 KB per input row
constexpr int OUT_ROW_F4 = WW * KK * KK * CH4;  // 25600 float4 per output row
constexpr int THREADS    = 1024;
constexpr int ROWS_PER_BLK = 4;
constexpr int NWG        = BB * HH / ROWS_PER_BLK;  // 256 blocks
constexpr int SLOTS      = 8;                   // ring slots (power of 2)

typedef float f32x4 __attribute__((ext_vector_type(4)));

__global__ void __launch_bounds__(THREADS) extract_patch_kernel(
        const f32x4* __restrict__ in, f32x4* __restrict__ out) {
    __shared__ f32x4 lds[SLOTS * ROW_F4];       // 128 KB ring

    // XCD-chunked bijective swizzle (nwg=256, 256%8==0): b = XCD id.
    int bid = blockIdx.x;
    int lin = (bid & 7) * (NWG / 8) + (bid >> 3);
    int b     = lin >> 5;                       // image (one per XCD)
    int h0    = (lin & 31) * ROWS_PER_BLK;      // first output row of chunk

    int tid = threadIdx.x;
    const f32x4* img = in + (size_t)b * HH * ROW_F4;

    // ---- Initial fill: rows h0-2 .. h0+2 into ring slots (zeros if OOB) ----
    {
        f32x4 v0[5];
        #pragma unroll
        for (int i = 0; i < 5; ++i) {
            int gr = h0 - PAD + i;
            v0[i] = 0.f;
            if ((unsigned)gr < (unsigned)HH)        // block-uniform branch
                v0[i] = img[(size_t)gr * ROW_F4 + tid];
        }
        #pragma unroll
        for (int i = 0; i < 5; ++i) {
            int gr = h0 - PAD + i;
            lds[(gr & (SLOTS - 1)) * ROW_F4 + tid] = v0[i];
        }
    }
    __syncthreads();

    // ---- Per output row: prefetch next input row, stream stores ----
    for (int r = 0; r < ROWS_PER_BLK; ++r) {
        int h = h0 + r;

        // Prefetch the one new row the NEXT output row needs (gr = h+3):
        // row h+1 reads input rows h-1..h+3; only h+3 is not yet staged.
        // Issued before the store loop -> HBM latency hides under stores.
        bool do_pf = (r < ROWS_PER_BLK - 1);
        int  gr_pf = h + 3;
        f32x4 pf = 0.f;
        if (do_pf && (unsigned)gr_pf < (unsigned)HH)   // block-uniform
            pf = img[(size_t)gr_pf * ROW_F4 + tid];

        // 25 perfectly-coalesced float4 NT stores per thread.
        f32x4* rowout = out + ((size_t)lin * ROWS_PER_BLK + r) * OUT_ROW_F4;
        #pragma unroll 5
        for (int it = 0; it < OUT_ROW_F4 / THREADS; ++it) {
            int j  = tid + it * THREADS;
            int w  = j / 200;                        // 200 float4 per w
            int rr = j - w * 200;
            int kq = rr >> 3;                        // kh*5+kw
            int c4 = rr & 7;
            int kh = (kq * 205) >> 10;               // kq/5 exact for 0..24
            int kw = kq - kh * 5;
            int pc = w + kw - PAD;                   // padded col, -2..129
            int gr = h + kh - PAD;                   // staged row
            int slot = gr & (SLOTS - 1);
            bool ok = (unsigned)pc < (unsigned)WW;
            f32x4 v = lds[slot * ROW_F4 + (pc & (WW - 1)) * CH4 + c4];
            f32x4 z = 0.f;
            v = ok ? v : z;                          // branchless col padding
            __builtin_nontemporal_store(v, &rowout[j]);
        }

        // Land the prefetched row in its ring slot (that slot last held
        // gr_pf-8, dead for 3 rows). The vmcnt wait for `pf` lands here,
        // after the store stream — latency fully hidden.
        if (do_pf)
            lds[(gr_pf & (SLOTS - 1)) * ROW_F4 + tid] = pf;
        __syncthreads();
    }
}

extern "C" void kernel_launch(void* const* d_in, const int* in_sizes, int n_in,
                              void* d_out, int out_size, void* d_ws, size_t ws_size,
                              hipStream_t stream) {
    const f32x4* images = (const f32x4*)d_in[0];
    f32x4* out = (f32x4*)d_out;
    extract_patch_kernel<<<NWG, THREADS, 0, stream>>>(images, out);
}